// Round 9
// baseline (63.978 us; speedup 1.0000x reference)
//
#include <hip/hip_runtime.h>

typedef __bf16 bf16x8 __attribute__((ext_vector_type(8)));
typedef float f32x4 __attribute__((ext_vector_type(4)));
typedef unsigned int uint;

#define XA_STR 152   // shorts; 304B rows, 16B-aligned

union Frag { __bf16 b[8]; bf16x8 v; unsigned short u[8]; };

__device__ __forceinline__ unsigned short bfbits(float f) {
  union { __bf16 h; unsigned short s; } c; c.h = (__bf16)f; return c.s;
}
__device__ __forceinline__ float bf2f(unsigned short h) {
  return __uint_as_float(((uint)h) << 16);
}

// asm-pinned loads: issue order fixed among volatile asms; WAITV counts them.
#define GL1(dst, voff, base, IMM) \
  asm volatile("global_load_dword %0, %1, %2 offset:" #IMM : "=v"(dst) : "v"(voff), "s"(base))
#define GL4(dst, voff, base) \
  asm volatile("global_load_dwordx4 %0, %1, %2" : "=v"(dst) : "v"(voff), "s"(base))
// rule #18: sched_barrier(0) after the wait so register consumers can't hoist
#define WAITV(N) do { asm volatile("s_waitcnt vmcnt(" #N ")" ::: "memory"); \
  __builtin_amdgcn_sched_barrier(0); } while (0)
#define BARX() asm volatile("s_waitcnt lgkmcnt(0)\n\ts_barrier" ::: "memory")

// dst[s][b][f] (bf16) = src[b][f][s]   (B=64, F=128, S=128)
template <typename T>
__global__ __launch_bounds__(256) void transpose_in(const T* __restrict__ src,
                                                    unsigned short* __restrict__ dst) {
  __shared__ unsigned short tile[64][68];
  const int b  = blockIdx.x >> 2;
  const int f0 = ((blockIdx.x >> 1) & 1) * 64;
  const int s0 = (blockIdx.x & 1) * 64;
  const int j = threadIdx.x & 63, i0 = threadIdx.x >> 6;
  const T* sp = src + b * 16384 + f0 * 128 + s0 + j;
#pragma unroll
  for (int p = 0; p < 16; ++p) {
    const int i = i0 + p * 4;
    if constexpr (sizeof(T) == 4) tile[i][j] = bfbits((float)sp[i * 128]);
    else                          tile[i][j] = (unsigned short)sp[i * 128];
  }
  __syncthreads();
  unsigned short* dp = dst + s0 * 8192 + b * 128 + f0 + j;
#pragma unroll
  for (int p = 0; p < 16; ++p) {
    const int i = i0 + p * 4;
    dp[(size_t)i * 8192] = tile[j][i];
  }
}

// Block = (slot s, E-quarter q): 512 threads = 8 waves; wave owns 16 weight
// cols. ALL 96 weight loads burst-issued up front into asm-pinned VGPRs
// (wave rides the vmcnt~63 hardware cap, ~16KB/wave in flight), consumed
// with a monotone counted-vmcnt ladder. No weight LDS, 3 barriers total.
__global__ __launch_bounds__(512, 2) void mlp_main(
    const unsigned short* __restrict__ Xt,   // [128][64][128] bf16
    const float* __restrict__ Wu, const float* __restrict__ bu,
    const float* __restrict__ Wg, const float* __restrict__ bg,
    const float* __restrict__ Wd,
    unsigned short* __restrict__ partial)    // [512][64][128] bf16
{
  const int bid = blockIdx.x;
  const int s = bid >> 2, q = bid & 3;
  const int tid = threadIdx.x;
  const int wv = tid >> 6, lane = tid & 63;
  const int l16 = lane & 15, lg = lane >> 4;
  const int col = wv * 16 + l16;

  __shared__ __align__(16) unsigned short xa[64 * XA_STR]; // X then A2

  const float* WuS = Wu + (size_t)s * 65536;
  const float* WgS = Wg + (size_t)s * 65536;
  const float* WdS = Wd + (size_t)s * 65536;
  const unsigned short* XtS = Xt + (size_t)s * 8192;

  // byte voffsets; up/gate element (k=kk*32+lg*8+j, e=q*128+col), row 2048B
  uint vu = (uint)(((lg * 8) * 512 + q * 128 + col) * 4);
  // down element (e=q*128+kk*32+lg*8+j, d=col), row 512B
  uint vd = (uint)(((q * 128 + lg * 8) * 128 + col) * 4);
  const uint vbo = (uint)((q * 128 + col) * 4);
  const uint vx0 = (uint)(tid * 16), vx1 = vx0 + 8192;

  float u0[8], g0[8], u1[8], g1[8], u2[8], g2[8], u3[8], g3[8];
  float d0[8], d1[8], d2[8], d3[8];
  f32x4 xq0, xq1;
  float buv, bgv;

#define ISSUE_UG(U, G) do { \
  GL1(U[0], vu, WuS, 0); GL1(U[1], vu, WuS, 2048); \
  GL1(G[0], vu, WgS, 0); GL1(G[1], vu, WgS, 2048); vu += 4096; \
  GL1(U[2], vu, WuS, 0); GL1(U[3], vu, WuS, 2048); \
  GL1(G[2], vu, WgS, 0); GL1(G[3], vu, WgS, 2048); vu += 4096; \
  GL1(U[4], vu, WuS, 0); GL1(U[5], vu, WuS, 2048); \
  GL1(G[4], vu, WgS, 0); GL1(G[5], vu, WgS, 2048); vu += 4096; \
  GL1(U[6], vu, WuS, 0); GL1(U[7], vu, WuS, 2048); \
  GL1(G[6], vu, WgS, 0); GL1(G[7], vu, WgS, 2048); vu += 53248; /* next kk */ \
} while (0)

#define ISSUE_D(D) do { \
  GL1(D[0], vd, WdS, 0);    GL1(D[1], vd, WdS, 512); \
  GL1(D[2], vd, WdS, 1024); GL1(D[3], vd, WdS, 1536); \
  GL1(D[4], vd, WdS, 2048); GL1(D[5], vd, WdS, 2560); \
  GL1(D[6], vd, WdS, 3072); GL1(D[7], vd, WdS, 3584); vd += 16384; \
} while (0)

  Frag a[4];
#define LOADA(KK) do { \
  _Pragma("unroll") \
  for (int mt = 0; mt < 4; ++mt) \
    a[mt].v = *(const bf16x8*)&xa[(mt * 16 + l16) * XA_STR + (((KK) * 4 + lg) << 3)]; \
} while (0)

  f32x4 au[4] = {}, ag[4] = {}, ad[4] = {};
#define STEP_UG(U, G) do { \
  Frag fu, fg; \
  _Pragma("unroll") \
  for (int j = 0; j < 8; ++j) { fu.b[j] = (__bf16)U[j]; fg.b[j] = (__bf16)G[j]; } \
  _Pragma("unroll") \
  for (int mt = 0; mt < 4; ++mt) { \
    au[mt] = __builtin_amdgcn_mfma_f32_16x16x32_bf16(a[mt].v, fu.v, au[mt], 0, 0, 0); \
    ag[mt] = __builtin_amdgcn_mfma_f32_16x16x32_bf16(a[mt].v, fg.v, ag[mt], 0, 0, 0); } \
} while (0)

#define STEP_D(D) do { \
  Frag fd; \
  _Pragma("unroll") \
  for (int j = 0; j < 8; ++j) fd.b[j] = (__bf16)D[j]; \
  _Pragma("unroll") \
  for (int mt = 0; mt < 4; ++mt) \
    ad[mt] = __builtin_amdgcn_mfma_f32_16x16x32_bf16(a[mt].v, fd.v, ad[mt], 0, 0, 0); \
} while (0)

  // ---- phase 0: X + biases, fully drained (clean vmcnt ledger) ----
  GL4(xq0, vx0, XtS);
  GL4(xq1, vx1, XtS);
  GL1(buv, vbo, bu + s * 512, 0);
  GL1(bgv, vbo, bg + s * 512, 0);
  WAITV(0);
  {
    const int m0 = tid >> 4, ch0 = tid & 15;
    *(f32x4*)&xa[m0 * XA_STR + (ch0 << 3)] = xq0;
    const int p1 = tid + 512, m1 = p1 >> 4, ch1 = p1 & 15;
    *(f32x4*)&xa[m1 * XA_STR + (ch1 << 3)] = xq1;
  }
  BARX();                                 // xa visible to all waves

  // ---- phase 1: burst-issue ALL 96 weight loads ----
  ISSUE_UG(u0, g0);                       // 16 outstanding
  ISSUE_UG(u1, g1);                       // 32
  ISSUE_UG(u2, g2);                       // 48
  ISSUE_UG(u3, g3);                       // 64
  ISSUE_D(d0);                            // 72
  ISSUE_D(d1);                            // 80
  ISSUE_D(d2);                            // 88
  ISSUE_D(d3);                            // 96 (HW caps ~63; tail trickles out)

  // ---- phase 2: consume with monotone vmcnt ladder ----
  WAITV(63); LOADA(0); STEP_UG(u0, g0);   // need <=80; 63 is stricter, ok
  WAITV(63); LOADA(1); STEP_UG(u1, g1);   // need <=64
  WAITV(48); LOADA(2); STEP_UG(u2, g2);
  WAITV(32); LOADA(3); STEP_UG(u3, g3);

  // silu epilogue -> A2 into xa
  float a2v[4][4];
#pragma unroll
  for (int mt = 0; mt < 4; ++mt)
#pragma unroll
    for (int r = 0; r < 4; ++r) {
      const float uv = au[mt][r] + buv;
      const float gv = ag[mt][r] + bgv;
      a2v[mt][r] = uv * (gv / (1.f + __expf(-gv)));
    }
  BARX();                                 // all waves done reading X
#pragma unroll
  for (int mt = 0; mt < 4; ++mt)
#pragma unroll
    for (int r = 0; r < 4; ++r)
      xa[(mt * 16 + lg * 4 + r) * XA_STR + col] = bfbits(a2v[mt][r]);
  BARX();                                 // A2 visible

  WAITV(24); LOADA(0); STEP_D(d0);
  WAITV(16); LOADA(1); STEP_D(d1);
  WAITV(8);  LOADA(2); STEP_D(d2);
  WAITV(0);  LOADA(3); STEP_D(d3);

  unsigned short* po = partial + (size_t)bid * 8192;
#pragma unroll
  for (int mt = 0; mt < 4; ++mt)
#pragma unroll
    for (int r = 0; r < 4; ++r)
      po[(mt * 16 + lg * 4 + r) * 128 + col] = bfbits(ad[mt][r]);

#undef ISSUE_UG
#undef ISSUE_D
#undef LOADA
#undef STEP_UG
#undef STEP_D
}

// sum 4 bf16 partials + bias + residual(xt [s][b][f]), RMSNorm, write [b][s][f]
template <typename TO>
__global__ __launch_bounds__(256) void finish(
    const unsigned short* __restrict__ part, const unsigned short* __restrict__ xt,
    const float* __restrict__ bd, const float* __restrict__ scale,
    TO* __restrict__ y)
{
  const int s = blockIdx.x >> 1, half = blockIdx.x & 1;
  const int wvt = threadIdx.x >> 6, lane = threadIdx.x & 63;
  const int d0 = lane * 2;
  const float sc0 = scale[d0], sc1 = scale[d0 + 1];
  const float b0 = bd[s * 128 + d0], b1 = bd[s * 128 + d0 + 1];
  const unsigned short* pb = part + (size_t)s * 4 * 8192;
  const unsigned short* xb = xt + (size_t)s * 8192;
  for (int i = 0; i < 8; ++i) {
    const int b = half * 32 + i * 4 + wvt;
    const uint rx = *(const uint*)(xb + b * 128 + d0);
    float z0 = b0 + bf2f((unsigned short)rx);
    float z1 = b1 + bf2f((unsigned short)(rx >> 16));
#pragma unroll
    for (int p = 0; p < 4; ++p) {
      const uint rp = *(const uint*)(pb + p * 8192 + b * 128 + d0);
      z0 += bf2f((unsigned short)rp);
      z1 += bf2f((unsigned short)(rp >> 16));
    }
    float ss = z0 * z0 + z1 * z1;
#pragma unroll
    for (int off = 32; off; off >>= 1) ss += __shfl_xor(ss, off);
    const float inv = rsqrtf(ss * (1.f / 128.f) + 1e-5f);
    if constexpr (sizeof(TO) == 4) {
      float2 o = make_float2(z0 * inv * sc0, z1 * inv * sc1);
      *(float2*)((float*)y + (size_t)b * 16384 + s * 128 + d0) = o;
    } else {
      const uint o = (uint)bfbits(z0 * inv * sc0) | ((uint)bfbits(z1 * inv * sc1) << 16);
      *(uint*)((unsigned short*)y + (size_t)b * 16384 + s * 128 + d0) = o;
    }
  }
}

extern "C" void kernel_launch(void* const* d_in, const int* in_sizes, int n_in,
                              void* d_out, int out_size, void* d_ws, size_t ws_size,
                              hipStream_t stream) {
  (void)in_sizes; (void)n_in; (void)out_size; (void)ws_size;
  const float* x   = (const float*)d_in[0];
  const float* W1u = (const float*)d_in[1];
  const float* b1u = (const float*)d_in[2];
  const float* W1g = (const float*)d_in[3];
  const float* b1g = (const float*)d_in[4];
  const float* W1d = (const float*)d_in[5];
  const float* b1d = (const float*)d_in[6];
  const float* sc1 = (const float*)d_in[7];
  const float* W2u = (const float*)d_in[8];
  const float* b2u = (const float*)d_in[9];
  const float* W2g = (const float*)d_in[10];
  const float* b2g = (const float*)d_in[11];
  const float* W2d = (const float*)d_in[12];
  const float* b2d = (const float*)d_in[13];
  const float* sc2 = (const float*)d_in[14];
  float* out = (float*)d_out;

  unsigned short* xt   = (unsigned short*)d_ws;          // 2 MB [s][b][f] bf16
  unsigned short* y1   = xt + (size_t)1048576;           // 2 MB [b][s][f] bf16
  unsigned short* part = y1 + (size_t)1048576;           // 8 MB [512][64][128] bf16

  transpose_in<float><<<256, 256, 0, stream>>>(x, xt);
  mlp_main<<<512, 512, 0, stream>>>(xt, W1u, b1u, W1g, b1g, W1d, part);
  finish<unsigned short><<<256, 256, 0, stream>>>(part, xt, b1d, sc1, y1);
  transpose_in<unsigned short><<<256, 256, 0, stream>>>(y1, xt);
  mlp_main<<<512, 512, 0, stream>>>(xt, W2u, b2u, W2g, b2g, W2d, part);
  finish<float><<<256, 256, 0, stream>>>(part, xt, b2d, sc2, out);
}

// Round 10
// 60.149 us; speedup vs baseline: 1.0637x; 1.0637x over previous
//
#include <hip/hip_runtime.h>

typedef __bf16 bf16x8 __attribute__((ext_vector_type(8)));
typedef float f32x4 __attribute__((ext_vector_type(4)));
typedef unsigned int uint;

#define XA_STR 152   // shorts; 304B rows, 16B-aligned

union Frag { __bf16 b[8]; bf16x8 v; unsigned short u[8]; };

__device__ __forceinline__ unsigned short bfbits(float f) {
  union { __bf16 h; unsigned short s; } c; c.h = (__bf16)f; return c.s;
}
__device__ __forceinline__ float bf2f(unsigned short h) {
  return __uint_as_float(((uint)h) << 16);
}

// asm-pinned loads: issue order fixed among volatile asms; WAITV counts them.
#define GL1(dst, voff, base, IMM) \
  asm volatile("global_load_dword %0, %1, %2 offset:" #IMM : "=v"(dst) : "v"(voff), "s"(base))
#define GL4(dst, voff, base) \
  asm volatile("global_load_dwordx4 %0, %1, %2" : "=v"(dst) : "v"(voff), "s"(base))
#define WAITV(N) do { asm volatile("s_waitcnt vmcnt(" #N ")" ::: "memory"); \
  __builtin_amdgcn_sched_barrier(0); } while (0)
#define BARX() asm volatile("s_waitcnt lgkmcnt(0)\n\ts_barrier" ::: "memory")

// dst[s][b][f] (bf16) = src[b][f][s]   (B=64, F=128, S=128), fp32 src
__global__ __launch_bounds__(256) void transpose_in(const float* __restrict__ src,
                                                    unsigned short* __restrict__ dst) {
  __shared__ unsigned short tile[64][68];
  const int b  = blockIdx.x >> 2;
  const int f0 = ((blockIdx.x >> 1) & 1) * 64;
  const int s0 = (blockIdx.x & 1) * 64;
  const int j = threadIdx.x & 63, i0 = threadIdx.x >> 6;
  const float* sp = src + b * 16384 + f0 * 128 + s0 + j;
#pragma unroll
  for (int p = 0; p < 16; ++p) {
    const int i = i0 + p * 4;
    tile[i][j] = bfbits(sp[i * 128]);
  }
  __syncthreads();
  unsigned short* dp = dst + s0 * 8192 + b * 128 + f0 + j;
#pragma unroll
  for (int p = 0; p < 16; ++p) {
    const int i = i0 + p * 4;
    dp[(size_t)i * 8192] = tile[j][i];
  }
}

// Block = (slot s, E-quarter q): 512 threads = 8 waves; wave owns 16 weight
// cols. ALL 96 weight loads burst-issued up front into asm-pinned VGPRs,
// consumed with a monotone counted-vmcnt ladder. (Round-9 kernel, unchanged.)
__global__ __launch_bounds__(512, 2) void mlp_main(
    const unsigned short* __restrict__ Xt,   // [128][64][128] bf16
    const float* __restrict__ Wu, const float* __restrict__ bu,
    const float* __restrict__ Wg, const float* __restrict__ bg,
    const float* __restrict__ Wd,
    unsigned short* __restrict__ partial)    // [512][64][128] bf16
{
  const int bid = blockIdx.x;
  const int s = bid >> 2, q = bid & 3;
  const int tid = threadIdx.x;
  const int wv = tid >> 6, lane = tid & 63;
  const int l16 = lane & 15, lg = lane >> 4;
  const int col = wv * 16 + l16;

  __shared__ __align__(16) unsigned short xa[64 * XA_STR]; // X then A2

  const float* WuS = Wu + (size_t)s * 65536;
  const float* WgS = Wg + (size_t)s * 65536;
  const float* WdS = Wd + (size_t)s * 65536;
  const unsigned short* XtS = Xt + (size_t)s * 8192;

  uint vu = (uint)(((lg * 8) * 512 + q * 128 + col) * 4);
  uint vd = (uint)(((q * 128 + lg * 8) * 128 + col) * 4);
  const uint vbo = (uint)((q * 128 + col) * 4);
  const uint vx0 = (uint)(tid * 16), vx1 = vx0 + 8192;

  float u0[8], g0[8], u1[8], g1[8], u2[8], g2[8], u3[8], g3[8];
  float d0[8], d1[8], d2[8], d3[8];
  f32x4 xq0, xq1;
  float buv, bgv;

#define ISSUE_UG(U, G) do { \
  GL1(U[0], vu, WuS, 0); GL1(U[1], vu, WuS, 2048); \
  GL1(G[0], vu, WgS, 0); GL1(G[1], vu, WgS, 2048); vu += 4096; \
  GL1(U[2], vu, WuS, 0); GL1(U[3], vu, WuS, 2048); \
  GL1(G[2], vu, WgS, 0); GL1(G[3], vu, WgS, 2048); vu += 4096; \
  GL1(U[4], vu, WuS, 0); GL1(U[5], vu, WuS, 2048); \
  GL1(G[4], vu, WgS, 0); GL1(G[5], vu, WgS, 2048); vu += 4096; \
  GL1(U[6], vu, WuS, 0); GL1(U[7], vu, WuS, 2048); \
  GL1(G[6], vu, WgS, 0); GL1(G[7], vu, WgS, 2048); vu += 53248; \
} while (0)

#define ISSUE_D(D) do { \
  GL1(D[0], vd, WdS, 0);    GL1(D[1], vd, WdS, 512); \
  GL1(D[2], vd, WdS, 1024); GL1(D[3], vd, WdS, 1536); \
  GL1(D[4], vd, WdS, 2048); GL1(D[5], vd, WdS, 2560); \
  GL1(D[6], vd, WdS, 3072); GL1(D[7], vd, WdS, 3584); vd += 16384; \
} while (0)

  Frag a[4];
#define LOADA(KK) do { \
  _Pragma("unroll") \
  for (int mt = 0; mt < 4; ++mt) \
    a[mt].v = *(const bf16x8*)&xa[(mt * 16 + l16) * XA_STR + (((KK) * 4 + lg) << 3)]; \
} while (0)

  f32x4 au[4] = {}, ag[4] = {}, ad[4] = {};
#define STEP_UG(U, G) do { \
  Frag fu, fg; \
  _Pragma("unroll") \
  for (int j = 0; j < 8; ++j) { fu.b[j] = (__bf16)U[j]; fg.b[j] = (__bf16)G[j]; } \
  _Pragma("unroll") \
  for (int mt = 0; mt < 4; ++mt) { \
    au[mt] = __builtin_amdgcn_mfma_f32_16x16x32_bf16(a[mt].v, fu.v, au[mt], 0, 0, 0); \
    ag[mt] = __builtin_amdgcn_mfma_f32_16x16x32_bf16(a[mt].v, fg.v, ag[mt], 0, 0, 0); } \
} while (0)

#define STEP_D(D) do { \
  Frag fd; \
  _Pragma("unroll") \
  for (int j = 0; j < 8; ++j) fd.b[j] = (__bf16)D[j]; \
  _Pragma("unroll") \
  for (int mt = 0; mt < 4; ++mt) \
    ad[mt] = __builtin_amdgcn_mfma_f32_16x16x32_bf16(a[mt].v, fd.v, ad[mt], 0, 0, 0); \
} while (0)

  // phase 0: X + biases, fully drained
  GL4(xq0, vx0, XtS);
  GL4(xq1, vx1, XtS);
  GL1(buv, vbo, bu + s * 512, 0);
  GL1(bgv, vbo, bg + s * 512, 0);
  WAITV(0);
  {
    const int m0 = tid >> 4, ch0 = tid & 15;
    *(f32x4*)&xa[m0 * XA_STR + (ch0 << 3)] = xq0;
    const int p1 = tid + 512, m1 = p1 >> 4, ch1 = p1 & 15;
    *(f32x4*)&xa[m1 * XA_STR + (ch1 << 3)] = xq1;
  }
  BARX();

  // phase 1: burst-issue all 96 weight loads
  ISSUE_UG(u0, g0);
  ISSUE_UG(u1, g1);
  ISSUE_UG(u2, g2);
  ISSUE_UG(u3, g3);
  ISSUE_D(d0);
  ISSUE_D(d1);
  ISSUE_D(d2);
  ISSUE_D(d3);

  // phase 2: monotone vmcnt ladder
  WAITV(63); LOADA(0); STEP_UG(u0, g0);
  WAITV(63); LOADA(1); STEP_UG(u1, g1);
  WAITV(48); LOADA(2); STEP_UG(u2, g2);
  WAITV(32); LOADA(3); STEP_UG(u3, g3);

  float a2v[4][4];
#pragma unroll
  for (int mt = 0; mt < 4; ++mt)
#pragma unroll
    for (int r = 0; r < 4; ++r) {
      const float uv = au[mt][r] + buv;
      const float gv = ag[mt][r] + bgv;
      a2v[mt][r] = uv * (gv / (1.f + __expf(-gv)));
    }
  BARX();
#pragma unroll
  for (int mt = 0; mt < 4; ++mt)
#pragma unroll
    for (int r = 0; r < 4; ++r)
      xa[(mt * 16 + lg * 4 + r) * XA_STR + col] = bfbits(a2v[mt][r]);
  BARX();

  WAITV(24); LOADA(0); STEP_D(d0);
  WAITV(16); LOADA(1); STEP_D(d1);
  WAITV(8);  LOADA(2); STEP_D(d2);
  WAITV(0);  LOADA(3); STEP_D(d3);

  unsigned short* po = partial + (size_t)bid * 8192;
#pragma unroll
  for (int mt = 0; mt < 4; ++mt)
#pragma unroll
    for (int r = 0; r < 4; ++r)
      po[(mt * 16 + lg * 4 + r) * 128 + col] = bfbits(ad[mt][r]);

#undef ISSUE_UG
#undef ISSUE_D
#undef LOADA
#undef STEP_UG
#undef STEP_D
}

// Layer-1 finish, b-major, FUSED transpose-out:
// block=(b, s-quarter sq); wave holds a full d-row per s.
// z[b,s,d] = sum_q part + bias + residual(xt1), RMSNorm over d,
// written TRANSPOSED: xt2[d][b][s] (the layer-2 staging layout) via LDS tile.
__global__ __launch_bounds__(256) void finish1(
    const unsigned short* __restrict__ part, const unsigned short* __restrict__ xt1,
    const float* __restrict__ bd, const float* __restrict__ scale,
    unsigned short* __restrict__ xt2)
{
  const int b = blockIdx.x >> 2, sq = blockIdx.x & 3;
  const int wvt = threadIdx.x >> 6, lane = threadIdx.x & 63;
  const int d0 = lane * 2;
  const float sc0 = scale[d0], sc1 = scale[d0 + 1];
  __shared__ unsigned short zt[128][40];   // [d][s_local], 80B rows (16B-mult)

  for (int i = 0; i < 8; ++i) {
    const int sl = i * 4 + wvt;            // 0..31
    const int s = sq * 32 + sl;
    const uint rx = *(const uint*)(xt1 + (size_t)s * 8192 + b * 128 + d0);
    float z0 = bd[s * 128 + d0]     + bf2f((unsigned short)rx);
    float z1 = bd[s * 128 + d0 + 1] + bf2f((unsigned short)(rx >> 16));
#pragma unroll
    for (int p = 0; p < 4; ++p) {
      const uint rp = *(const uint*)(part + ((size_t)(s * 4 + p)) * 8192 + b * 128 + d0);
      z0 += bf2f((unsigned short)rp);
      z1 += bf2f((unsigned short)(rp >> 16));
    }
    float ss = z0 * z0 + z1 * z1;
#pragma unroll
    for (int off = 32; off; off >>= 1) ss += __shfl_xor(ss, off);
    const float inv = rsqrtf(ss * (1.f / 128.f) + 1e-5f);
    zt[d0][sl]     = bfbits(z0 * inv * sc0);
    zt[d0 + 1][sl] = bfbits(z1 * inv * sc1);
  }
  __syncthreads();
  // write phase: thread t covers output row d = t>>1, s-half so = (t&1)*16
  const int dd = threadIdx.x >> 1, so = (threadIdx.x & 1) * 16;
  unsigned short* dst = xt2 + (size_t)dd * 8192 + b * 128 + sq * 32 + so;
  const uint4* srcv = (const uint4*)&zt[dd][so];
  ((uint4*)dst)[0] = srcv[0];
  ((uint4*)dst)[1] = srcv[1];
}

// Layer-2 finish, b-major: block=(b, s-quarter); writes out[b][t][j] fp32
// coalesced. Residual = xt2[t][b][j].
__global__ __launch_bounds__(256) void finish2(
    const unsigned short* __restrict__ part, const unsigned short* __restrict__ xt2,
    const float* __restrict__ bd, const float* __restrict__ scale,
    float* __restrict__ out)
{
  const int b = blockIdx.x >> 2, sq = blockIdx.x & 3;
  const int wvt = threadIdx.x >> 6, lane = threadIdx.x & 63;
  const int d0 = lane * 2;
  const float sc0 = scale[d0], sc1 = scale[d0 + 1];
  for (int i = 0; i < 8; ++i) {
    const int s = sq * 32 + i * 4 + wvt;
    const uint rx = *(const uint*)(xt2 + (size_t)s * 8192 + b * 128 + d0);
    float z0 = bd[s * 128 + d0]     + bf2f((unsigned short)rx);
    float z1 = bd[s * 128 + d0 + 1] + bf2f((unsigned short)(rx >> 16));
#pragma unroll
    for (int p = 0; p < 4; ++p) {
      const uint rp = *(const uint*)(part + ((size_t)(s * 4 + p)) * 8192 + b * 128 + d0);
      z0 += bf2f((unsigned short)rp);
      z1 += bf2f((unsigned short)(rp >> 16));
    }
    float ss = z0 * z0 + z1 * z1;
#pragma unroll
    for (int off = 32; off; off >>= 1) ss += __shfl_xor(ss, off);
    const float inv = rsqrtf(ss * (1.f / 128.f) + 1e-5f);
    *(float2*)(out + (size_t)b * 16384 + s * 128 + d0) =
        make_float2(z0 * inv * sc0, z1 * inv * sc1);
  }
}

extern "C" void kernel_launch(void* const* d_in, const int* in_sizes, int n_in,
                              void* d_out, int out_size, void* d_ws, size_t ws_size,
                              hipStream_t stream) {
  (void)in_sizes; (void)n_in; (void)out_size; (void)ws_size;
  const float* x   = (const float*)d_in[0];
  const float* W1u = (const float*)d_in[1];
  const float* b1u = (const float*)d_in[2];
  const float* W1g = (const float*)d_in[3];
  const float* b1g = (const float*)d_in[4];
  const float* W1d = (const float*)d_in[5];
  const float* b1d = (const float*)d_in[6];
  const float* sc1 = (const float*)d_in[7];
  const float* W2u = (const float*)d_in[8];
  const float* b2u = (const float*)d_in[9];
  const float* W2g = (const float*)d_in[10];
  const float* b2g = (const float*)d_in[11];
  const float* W2d = (const float*)d_in[12];
  const float* b2d = (const float*)d_in[13];
  const float* sc2 = (const float*)d_in[14];
  float* out = (float*)d_out;

  unsigned short* xt1  = (unsigned short*)d_ws;          // 2 MB [s][b][f] bf16
  unsigned short* xt2  = xt1 + (size_t)1048576;          // 2 MB [t][b][f] bf16
  unsigned short* part = xt2 + (size_t)1048576;          // 8 MB [512][64][128] bf16

  transpose_in<<<256, 256, 0, stream>>>(x, xt1);
  mlp_main<<<512, 512, 0, stream>>>(xt1, W1u, b1u, W1g, b1g, W1d, part);
  finish1<<<256, 256, 0, stream>>>(part, xt1, b1d, sc1, xt2);
  mlp_main<<<512, 512, 0, stream>>>(xt2, W2u, b2u, W2g, b2g, W2d, part);
  finish2<<<256, 256, 0, stream>>>(part, xt2, b2d, sc2, out);
}